// Round 17
// baseline (967.353 us; speedup 1.0000x reference)
//
#include <hip/hip_runtime.h>

// HyperbolicAttention: N=100000 nodes, C=128, H=8 heads, D=16, E=640000 edges.
// Round 17: r15 GEMMs (single-tile one-shot blocks, validated local optimum;
//           r9/r10/r11/r16 variants all falsified) + DEGREE-SORTED gather:
//           counting-sort nodes by degree (64 bins) so each 64-lane wave
//           processes near-uniform-degree nodes (kills wave-max skew).

#define TPB 256

typedef __attribute__((ext_vector_type(8))) short short8;
typedef __attribute__((ext_vector_type(4))) short short4v;
typedef __attribute__((ext_vector_type(4))) float f32x4;

// fp32 -> bf16 round-to-nearest-even
__device__ __forceinline__ short f2bf(float f) {
    unsigned u = __float_as_uint(f);
    u += 0x7fffu + ((u >> 16) & 1u);
    return (short)(u >> 16);
}
// bf16 -> fp32
__device__ __forceinline__ float bf2f(short s) {
    return __uint_as_float(((unsigned)(unsigned short)s) << 16);
}

// ---------------------------------------------------------------------------
// Shared GEMM body (r15, validated): one 128-row tile per block; W staged via
// async global_load_lds (frag-major); all X loads issued before any wait;
// swapped-operand MFMA; vectorized stores.
// ---------------------------------------------------------------------------
template<bool IN_BF16, bool OUT_BF16>
__device__ __forceinline__ void gemm_body(
    const void* __restrict__ Xv, int nrows,
    const short* __restrict__ Wb, const float* __restrict__ bias,
    void* __restrict__ Yv, int xblk)
{
    __shared__ short lw[16384];   // 32 KiB W, frag-major
    const int tid = threadIdx.x;

    #pragma unroll
    for (int r = 0; r < 8; ++r) {
        int c = r * 256 + tid;              // chunk id 0..2047
        int fragid = c >> 6, ln = c & 63;
        int n = fragid >> 2, kc = fragid & 3;
        const short* gsrc = &Wb[(n*16 + (ln & 15))*128 + kc*32 + (ln >> 4)*8];
        __builtin_amdgcn_global_load_lds(
            (const __attribute__((address_space(1))) void*)gsrc,
            (__attribute__((address_space(3))) void*)&lw[c * 8],
            16, 0, 0);
    }

    const int wid = tid >> 6;
    const int lane = tid & 63;
    const int l15 = lane & 15;
    const int lh  = lane >> 4;
    const int rowbase = xblk * 128 + wid * 32;
    const int r0 = rowbase + l15, r1 = r0 + 16;
    const bool vv0 = r0 < nrows, vv1 = r1 < nrows;

    short8 xfr[4][2];   // [kc][row-group]
    if (IN_BF16) {
        const short* Xb = (const short*)Xv;
        #pragma unroll
        for (int kc = 0; kc < 4; ++kc) {
            xfr[kc][0] = vv0 ? *(const short8*)&Xb[(size_t)r0*128 + kc*32 + lh*8]
                             : (short8)(short)0;
            xfr[kc][1] = vv1 ? *(const short8*)&Xb[(size_t)r1*128 + kc*32 + lh*8]
                             : (short8)(short)0;
        }
    } else {
        const float* Xf = (const float*)Xv;
        const float4* P0 = (const float4*)(Xf + (size_t)r0 * 128);
        const float4* P1 = (const float4*)(Xf + (size_t)r1 * 128);
        float4 xa[4][2], xb[4][2];
        #pragma unroll
        for (int kc = 0; kc < 4; ++kc) {
            xa[kc][0] = vv0 ? P0[kc*8 + lh*2]     : make_float4(0.f,0.f,0.f,0.f);
            xb[kc][0] = vv0 ? P0[kc*8 + lh*2 + 1] : make_float4(0.f,0.f,0.f,0.f);
            xa[kc][1] = vv1 ? P1[kc*8 + lh*2]     : make_float4(0.f,0.f,0.f,0.f);
            xb[kc][1] = vv1 ? P1[kc*8 + lh*2 + 1] : make_float4(0.f,0.f,0.f,0.f);
        }
        #pragma unroll
        for (int kc = 0; kc < 4; ++kc)
            #pragma unroll
            for (int g = 0; g < 2; ++g) {
                xfr[kc][g][0] = f2bf(xa[kc][g].x);
                xfr[kc][g][1] = f2bf(xa[kc][g].y);
                xfr[kc][g][2] = f2bf(xa[kc][g].z);
                xfr[kc][g][3] = f2bf(xa[kc][g].w);
                xfr[kc][g][4] = f2bf(xb[kc][g].x);
                xfr[kc][g][5] = f2bf(xb[kc][g].y);
                xfr[kc][g][6] = f2bf(xb[kc][g].z);
                xfr[kc][g][7] = f2bf(xb[kc][g].w);
            }
    }

    __syncthreads();   // drains vmcnt (global_load_lds) + barrier

    f32x4 acc[8][2];
    #pragma unroll
    for (int n = 0; n < 8; ++n) { acc[n][0] = (f32x4)0.f; acc[n][1] = (f32x4)0.f; }

    #pragma unroll
    for (int kc = 0; kc < 4; ++kc) {
        short8 wf[8];
        #pragma unroll
        for (int n = 0; n < 8; ++n)
            wf[n] = *(const short8*)&lw[((n*4 + kc)*64 + lane) * 8];
        #pragma unroll
        for (int n = 0; n < 8; ++n) {
            acc[n][0] = __builtin_amdgcn_mfma_f32_16x16x32_bf16(wf[n], xfr[kc][0], acc[n][0], 0, 0, 0);
            acc[n][1] = __builtin_amdgcn_mfma_f32_16x16x32_bf16(wf[n], xfr[kc][1], acc[n][1], 0, 0, 0);
        }
    }

    #pragma unroll
    for (int g = 0; g < 2; ++g) {
        int row = rowbase + g*16 + l15;
        if (row >= nrows) continue;
        #pragma unroll
        for (int n = 0; n < 8; ++n) {
            float4 b4 = *(const float4*)&bias[n*16 + lh*4];
            float y0 = acc[n][g][0] + b4.x;
            float y1 = acc[n][g][1] + b4.y;
            float y2 = acc[n][g][2] + b4.z;
            float y3 = acc[n][g][3] + b4.w;
            if (OUT_BF16) {
                short4v s; s[0]=f2bf(y0); s[1]=f2bf(y1); s[2]=f2bf(y2); s[3]=f2bf(y3);
                *(short4v*)&((short*)Yv)[(size_t)row * 128 + n*16 + lh*4] = s;
            } else {
                *(float4*)&((float*)Yv)[(size_t)row * 128 + n*16 + lh*4] =
                    make_float4(y0, y1, y2, y3);
            }
        }
    }
}

// Output projection: bf16 in, fp32 out.
__global__ __launch_bounds__(256) void gemm_out_kernel(
    const short* __restrict__ Xb, int nrows,
    const short* __restrict__ Wb, const float* __restrict__ bias,
    float* __restrict__ Y)
{
    gemm_body<true, false>(Xb, nrows, Wb, bias, Y, blockIdx.x);
}

// Fused QKV with XCD co-location: slices of X-tile x at b=(x&7)+8*(3*(x>>3)+w)
// share b%8 (same XCD) and are time-aligned -> X fetched once per XCD.
__global__ __launch_bounds__(256) void gemm_qkv_kernel(
    const float* __restrict__ X, int nrows, int nxblk,
    const short* __restrict__ WB,
    const float* __restrict__ bq, const float* __restrict__ bk,
    const float* __restrict__ bv,
    short* __restrict__ Yb, size_t slice)
{
    int b = blockIdx.x;
    int k = b & 7, j = b >> 3;
    int jd = j / 3, w = j - 3 * jd;
    int x = k + 8 * jd;
    if (x >= nxblk) return;
    const float* bias = (w == 0) ? bq : (w == 1) ? bk : bv;
    gemm_body<false, true>(X, nrows, WB + w * 16384, bias,
                           Yb + (size_t)w * slice, x);
}

// ---------------------------------------------------------------------------
// init: zero deg + degree-bin histogram + detect int64-vs-int32 edge_index.
// ---------------------------------------------------------------------------
__global__ void init_kernel(int* __restrict__ deg, int n,
                            int* __restrict__ dbin,
                            const int* __restrict__ raw, int* __restrict__ flag)
{
    int i = blockIdx.x * TPB + threadIdx.x;
    if (i < n) deg[i] = 0;
    if (blockIdx.x == 0 && threadIdx.x < 64) dbin[threadIdx.x] = 0;
    if (blockIdx.x == 0 && threadIdx.x == 0) {
        int odd_nonzero = 0;
        for (int k = 0; k < 128; ++k)
            if (raw[2 * k + 1] != 0) odd_nonzero = 1;
        *flag = odd_nonzero ? 0 : 1;  // 1 => int64 layout
    }
}

// ---------------------------------------------------------------------------
// conv_hist + wconv fused (r13, validated).
// ---------------------------------------------------------------------------
__global__ void conv_hist_wconv_kernel(
    const void* __restrict__ raw, int E, const int* __restrict__ flag,
    int* __restrict__ out, int* __restrict__ deg, int ebC,
    const float* __restrict__ W0, const float* __restrict__ W1,
    const float* __restrict__ W2, const float* __restrict__ W3,
    short* __restrict__ WB)
{
    int b = blockIdx.x;
    if (b < ebC) {
        int i = b * TPB + threadIdx.x;
        if (i >= 2 * E) return;
        int v;
        if (*flag) v = (int)((const long long*)raw)[i];
        else       v = ((const int*)raw)[i];
        out[i] = v;
        if (i < E) atomicAdd(&deg[v], 1);
    } else {
        int i = (b - ebC) * TPB + threadIdx.x;   // 0..65535
        if (i >= 65536) return;
        const float* W = (i < 16384) ? W0 : (i < 32768) ? W1 : (i < 49152) ? W2 : W3;
        WB[i] = f2bf(W[i & 16383]);
    }
}

// ---------------------------------------------------------------------------
// CSR scan chain; scan1 also histograms node degrees into 64 bins.
// ---------------------------------------------------------------------------
__global__ void scan1_kernel(const int* __restrict__ deg, int n,
                             int* __restrict__ rowstart, int* __restrict__ bsum,
                             int* __restrict__ dbin)
{
    __shared__ int sm[TPB];
    int t = threadIdx.x;
    int gid = blockIdx.x * TPB + t;
    int v = (gid < n) ? deg[gid] : 0;
    if (gid < n) atomicAdd(&dbin[v < 63 ? v : 63], 1);
    sm[t] = v;
    __syncthreads();
    for (int off = 1; off < TPB; off <<= 1) {
        int x = (t >= off) ? sm[t - off] : 0;
        __syncthreads();
        sm[t] += x;
        __syncthreads();
    }
    if (gid < n) rowstart[gid] = sm[t] - v;
    if (t == TPB - 1) bsum[blockIdx.x] = sm[t];
}

__global__ void scan2_kernel(int* __restrict__ bsum, int nb)
{
    __shared__ int sm[512];
    int t = threadIdx.x;
    int v = (t < nb) ? bsum[t] : 0;
    sm[t] = v;
    __syncthreads();
    for (int off = 1; off < 512; off <<= 1) {
        int x = (t >= off) ? sm[t - off] : 0;
        __syncthreads();
        sm[t] += x;
        __syncthreads();
    }
    if (t < nb) bsum[t] = sm[t] - v;
}

__global__ void scan3_kernel(int* __restrict__ rowstart, int* __restrict__ cursor,
                             int n, int E, const int* __restrict__ bsum)
{
    int gid = blockIdx.x * TPB + threadIdx.x;
    if (gid < n) {
        int v = rowstart[gid] + bsum[blockIdx.x];
        rowstart[gid] = v;
        cursor[gid] = v;
    }
    if (gid == 0) rowstart[n] = E;
}

// Exclusive scan of the 64 degree bins -> per-bin cursors.
__global__ void scan_deg_kernel(const int* __restrict__ dbin, int* __restrict__ dcur)
{
    __shared__ int sm[64];
    int t = threadIdx.x;   // 64 threads
    int v = dbin[t];
    sm[t] = v;
    __syncthreads();
    for (int off = 1; off < 64; off <<= 1) {
        int x = (t >= off) ? sm[t - off] : 0;
        __syncthreads();
        sm[t] += x;
        __syncthreads();
    }
    dcur[t] = sm[t] - v;
}

// Counting-sort scatter: nodeperm = node ids ordered by degree bin.
__global__ void fill_perm_kernel(const int* __restrict__ deg, int n,
                                 int* __restrict__ dcur, int* __restrict__ nodeperm)
{
    int i = blockIdx.x * TPB + threadIdx.x;
    if (i >= n) return;
    int d = deg[i];
    int pos = atomicAdd(&dcur[d < 63 ? d : 63], 1);
    nodeperm[pos] = i;
}

// Bin edges by destination: ecol[p] = source col, erow[p] = dest row.
__global__ void fill_kernel(const int* __restrict__ ei, int E,
                            int* __restrict__ cursor,
                            int* __restrict__ ecol, int* __restrict__ erow)
{
    int e = blockIdx.x * TPB + threadIdx.x;
    if (e >= E) return;
    int r = ei[e];
    int pos = atomicAdd(&cursor[r], 1);
    ecol[pos] = ei[E + e];
    erow[pos] = r;
}

// ---------------------------------------------------------------------------
// EDGE-PARALLEL scores + fused online softmax partials (r14, validated).
// ---------------------------------------------------------------------------
__global__ __launch_bounds__(256) void epar_score_stats_kernel(
    const short* __restrict__ Qb, const short* __restrict__ Kb,
    const int* __restrict__ erow, const int* __restrict__ ecol, int EH,
    float* __restrict__ S, float* __restrict__ mpart, float* __restrict__ zpart)
{
    int t = threadIdx.x;
    int stride = gridDim.x * TPB;
    float m = -3.0e38f, z = 0.f;
    for (int idx = blockIdx.x * TPB + t; idx < EH; idx += stride) {
        int p = idx >> 3, h = idx & 7;
        int r = erow[p], c = ecol[p];
        const short8* q8 = (const short8*)(Qb + (size_t)r * 128 + h * 16);
        const short8* k8 = (const short8*)(Kb + (size_t)c * 128 + h * 16);
        short8 q0 = q8[0], q1 = q8[1], k0 = k8[0], k1 = k8[1];
        float dot = 0.f;
        #pragma unroll
        for (int i = 0; i < 8; ++i) {
            dot += bf2f(q0[i]) * bf2f(k0[i]);
            dot += bf2f(q1[i]) * bf2f(k1[i]);
        }
        float s = dot * 0.25f;   // 1/sqrt(16)
        S[idx] = s;
        float M = fmaxf(m, s);
        z = z * __expf(m - M) + __expf(s - M);
        m = M;
    }
    __shared__ float sm[TPB], sz[TPB];
    sm[t] = m; sz[t] = z;
    __syncthreads();
    for (int off = 128; off >= 8; off >>= 1) {
        if (t < off) {
            float m2 = sm[t + off], z2 = sz[t + off];
            float M = fmaxf(sm[t], m2);
            sz[t] = sz[t] * __expf(sm[t] - M) + z2 * __expf(m2 - M);
            sm[t] = M;
        }
        __syncthreads();
    }
    if (t < 8) {
        mpart[blockIdx.x * 8 + t] = sm[t];
        zpart[blockIdx.x * 8 + t] = sz[t];
    }
}

// One block: combine nb per-block partials -> MZ[h] (max), MZ[8+h] (Z).
__global__ void stats_reduce_kernel(const float* __restrict__ mpart,
                                    const float* __restrict__ zpart,
                                    int nb, float* __restrict__ MZ)
{
    int t = threadIdx.x;
    int h = t & 7, chunk = t >> 3;   // 32 chunks
    float m = -3.0e38f, z = 0.f;
    for (int i = chunk; i < nb; i += 32) {
        float m2 = mpart[i * 8 + h], z2 = zpart[i * 8 + h];
        float M = fmaxf(m, m2);
        z = z * __expf(m - M) + z2 * __expf(m2 - M);
        m = M;
    }
    __shared__ float sm[TPB], sz[TPB];
    sm[t] = m; sz[t] = z;
    __syncthreads();
    for (int off = 128; off >= 8; off >>= 1) {
        if (t < off) {
            float m2 = sm[t + off], z2 = sz[t + off];
            float M = fmaxf(sm[t], m2);
            sz[t] = sz[t] * __expf(sm[t] - M) + z2 * __expf(m2 - M);
            sm[t] = M;
        }
        __syncthreads();
    }
    if (t < 8) { MZ[t] = sm[t]; MZ[8 + t] = sz[t]; }
}

// ---------------------------------------------------------------------------
// Gather segment-sum over DEGREE-SORTED nodes (nodeperm), fused exp/normalize,
// depth-2 prefetch. Waves now see near-uniform degrees -> no wave-max skew.
// ---------------------------------------------------------------------------
__global__ __launch_bounds__(256) void gather_kernel(
    const float* __restrict__ S, const short* __restrict__ Vb,
    const int* __restrict__ ecol,
    const int* __restrict__ rowstart,
    const int* __restrict__ nodeperm,
    const float* __restrict__ MZ, int N,
    short* __restrict__ outb)
{
    int idx = blockIdx.x * TPB + threadIdx.x;
    if (idx >= N * 8) return;
    int node = nodeperm[idx >> 3];
    int h = idx & 7;
    float M = MZ[h];
    float invZ = 1.0f / MZ[8 + h];
    int p0 = rowstart[node], p1 = rowstart[node + 1];

    float a[16];
    #pragma unroll
    for (int i = 0; i < 16; ++i) a[i] = 0.f;

    if (p0 < p1) {
        short8 va0, va1, vb0, vb1;
        float sa, sb;
        {
            const short8* vp = (const short8*)(Vb + (size_t)ecol[p0] * 128 + h * 16);
            va0 = vp[0]; va1 = vp[1];
            sa = S[(size_t)p0 * 8 + h];
        }
        if (p0 + 1 < p1) {
            const short8* vp = (const short8*)(Vb + (size_t)ecol[p0+1] * 128 + h * 16);
            vb0 = vp[0]; vb1 = vp[1];
            sb = S[(size_t)(p0+1) * 8 + h];
        } else { vb0 = va0; vb1 = va1; sb = sa; }

        for (int p = p0; p < p1; ++p) {
            short8 vc0 = vb0, vc1 = vb1;
            float sc = sb;
            if (p + 2 < p1) {
                const short8* vp = (const short8*)(Vb + (size_t)ecol[p+2] * 128 + h * 16);
                vc0 = vp[0]; vc1 = vp[1];
                sc = S[(size_t)(p+2) * 8 + h];
            }
            float w = __expf(sa - M) * invZ;
            #pragma unroll
            for (int i = 0; i < 8; ++i) {
                a[i]     += w * bf2f(va0[i]);
                a[8 + i] += w * bf2f(va1[i]);
            }
            va0 = vb0; va1 = vb1; vb0 = vc0; vb1 = vc1;
            sa = sb; sb = sc;
        }
    }
    short8 o0, o1;
    #pragma unroll
    for (int i = 0; i < 8; ++i) { o0[i] = f2bf(a[i]); o1[i] = f2bf(a[8 + i]); }
    short8* ob = (short8*)(outb + (size_t)node * 128 + h * 16);
    ob[0] = o0; ob[1] = o1;
}

// ---------------------------------------------------------------------------
extern "C" void kernel_launch(void* const* d_in, const int* in_sizes, int n_in,
                              void* d_out, int out_size, void* d_ws, size_t ws_size,
                              hipStream_t stream)
{
    const float* feat = (const float*)d_in[0];
    const void*  eraw = d_in[1];
    const float* Wq = (const float*)d_in[2];
    const float* bq = (const float*)d_in[3];
    const float* Wk = (const float*)d_in[4];
    const float* bk = (const float*)d_in[5];
    const float* Wv = (const float*)d_in[6];
    const float* bv = (const float*)d_in[7];
    const float* Wo = (const float*)d_in[8];
    const float* bo = (const float*)d_in[9];

    const int N = in_sizes[0] / 128;
    const int E = in_sizes[1] / 2;
    const size_t NC = (size_t)N * 128;
    const int EH = E * 8;
    const int gbN = (N * 8 + TPB - 1) / TPB;   // node-head grid (gather)
    const int EG  = 2500;                      // edge-stats grid (grid-stride)

    // Workspace layout
    short* Qb   = (short*)d_ws;            // [N][128] bf16 (Q,K,V contiguous)
    short* Kb   = Qb + NC;
    short* Vb   = Kb + NC;
    short* ACCb = Vb + NC;                 // [N][128] bf16
    float* S    = (float*)(ACCb + NC);     // [E*8] scores, CSR order
    int*   EI   = (int*)(S + EH);          // int32 indices, 2*E
    short* WB   = (short*)(EI + 2 * E);    // 4 x 16384 bf16 weights
    float* mpart = (float*)(WB + 65536);   // [EG][8]
    float* zpart = mpart + (size_t)EG * 8;
    float* MZ    = zpart + (size_t)EG * 8; // 16: M[8], Z[8]
    int*   flag  = (int*)(MZ + 16);
    int* deg      = flag + 16;             // N
    int* rowstart = deg + N;               // N+1
    int* cursor   = rowstart + N + 1;      // N
    int* bsum     = cursor + N;            // 512
    int* ecol     = bsum + 512;            // E (binned source cols)
    int* erow     = ecol + E;              // E (binned dest rows)
    int* dbin     = erow + E;              // 64 degree bins
    int* dcur     = dbin + 64;             // 64 bin cursors
    int* nodeperm = dcur + 64;             // N (degree-sorted node order)

    const int nbS = (N + TPB - 1) / TPB;
    const int ebE = (E + TPB - 1) / TPB;
    const int ebC = (2 * E + TPB - 1) / TPB;

    // --- CSR build + degree sort (independent of GEMMs) ---
    init_kernel<<<nbS, TPB, 0, stream>>>(deg, N, dbin, (const int*)eraw, flag);
    conv_hist_wconv_kernel<<<ebC + 256, TPB, 0, stream>>>(
        eraw, E, flag, EI, deg, ebC, Wq, Wk, Wv, Wo, WB);
    scan1_kernel<<<nbS, TPB, 0, stream>>>(deg, N, rowstart, bsum, dbin);
    scan2_kernel<<<1, 512, 0, stream>>>(bsum, nbS);
    scan3_kernel<<<nbS, TPB, 0, stream>>>(rowstart, cursor, N, E, bsum);
    scan_deg_kernel<<<1, 64, 0, stream>>>(dbin, dcur);
    fill_kernel<<<ebE, TPB, 0, stream>>>(EI, E, cursor, ecol, erow);
    fill_perm_kernel<<<nbS, TPB, 0, stream>>>(deg, N, dcur, nodeperm);

    // --- Projections (r15 structure) ---
    const int gb = (N + 127) / 128;                 // X tiles
    const int qkvgrid = 8 * 3 * ((gb + 7) / 8);     // XCD-co-located mapping
    gemm_qkv_kernel<<<qkvgrid, TPB, 0, stream>>>(feat, N, gb, WB, bq, bk, bv, Qb, NC);

    // --- Scores + softmax stats (edge-parallel, CSR order) ---
    epar_score_stats_kernel<<<EG, TPB, 0, stream>>>(Qb, Kb, erow, ecol, EH,
                                                    S, mpart, zpart);
    stats_reduce_kernel<<<1, TPB, 0, stream>>>(mpart, zpart, EG, MZ);

    // --- Gather segment-sum (degree-sorted) -> bf16 ACC ---
    gather_kernel<<<gbN, TPB, 0, stream>>>(S, Vb, ecol, rowstart, nodeperm,
                                           MZ, N, ACCb);

    // --- Output projection (bf16 in, fp32 out) ---
    gemm_out_kernel<<<gb, TPB, 0, stream>>>(ACCb, N, WB + 3 * 16384, bo, (float*)d_out);
}

// Round 18
// 260.864 us; speedup vs baseline: 3.7083x; 3.7083x over previous
//
#include <hip/hip_runtime.h>

// HyperbolicAttention: N=100000 nodes, C=128, H=8 heads, D=16, E=640000 edges.
// Round 18: r17's degree-sorted gather with the atomic contention FIXED:
//           two-level counting sort (per-block LDS histograms; 64 global
//           atomics per block instead of 1 per node). GEMMs = r15 structure.

#define TPB 256

typedef __attribute__((ext_vector_type(8))) short short8;
typedef __attribute__((ext_vector_type(4))) short short4v;
typedef __attribute__((ext_vector_type(4))) float f32x4;

// fp32 -> bf16 round-to-nearest-even
__device__ __forceinline__ short f2bf(float f) {
    unsigned u = __float_as_uint(f);
    u += 0x7fffu + ((u >> 16) & 1u);
    return (short)(u >> 16);
}
// bf16 -> fp32
__device__ __forceinline__ float bf2f(short s) {
    return __uint_as_float(((unsigned)(unsigned short)s) << 16);
}

// ---------------------------------------------------------------------------
// Shared GEMM body (r15, validated): one 128-row tile per block; W staged via
// async global_load_lds (frag-major); all X loads issued before any wait;
// swapped-operand MFMA; vectorized stores.
// ---------------------------------------------------------------------------
template<bool IN_BF16, bool OUT_BF16>
__device__ __forceinline__ void gemm_body(
    const void* __restrict__ Xv, int nrows,
    const short* __restrict__ Wb, const float* __restrict__ bias,
    void* __restrict__ Yv, int xblk)
{
    __shared__ short lw[16384];   // 32 KiB W, frag-major
    const int tid = threadIdx.x;

    #pragma unroll
    for (int r = 0; r < 8; ++r) {
        int c = r * 256 + tid;              // chunk id 0..2047
        int fragid = c >> 6, ln = c & 63;
        int n = fragid >> 2, kc = fragid & 3;
        const short* gsrc = &Wb[(n*16 + (ln & 15))*128 + kc*32 + (ln >> 4)*8];
        __builtin_amdgcn_global_load_lds(
            (const __attribute__((address_space(1))) void*)gsrc,
            (__attribute__((address_space(3))) void*)&lw[c * 8],
            16, 0, 0);
    }

    const int wid = tid >> 6;
    const int lane = tid & 63;
    const int l15 = lane & 15;
    const int lh  = lane >> 4;
    const int rowbase = xblk * 128 + wid * 32;
    const int r0 = rowbase + l15, r1 = r0 + 16;
    const bool vv0 = r0 < nrows, vv1 = r1 < nrows;

    short8 xfr[4][2];   // [kc][row-group]
    if (IN_BF16) {
        const short* Xb = (const short*)Xv;
        #pragma unroll
        for (int kc = 0; kc < 4; ++kc) {
            xfr[kc][0] = vv0 ? *(const short8*)&Xb[(size_t)r0*128 + kc*32 + lh*8]
                             : (short8)(short)0;
            xfr[kc][1] = vv1 ? *(const short8*)&Xb[(size_t)r1*128 + kc*32 + lh*8]
                             : (short8)(short)0;
        }
    } else {
        const float* Xf = (const float*)Xv;
        const float4* P0 = (const float4*)(Xf + (size_t)r0 * 128);
        const float4* P1 = (const float4*)(Xf + (size_t)r1 * 128);
        float4 xa[4][2], xb[4][2];
        #pragma unroll
        for (int kc = 0; kc < 4; ++kc) {
            xa[kc][0] = vv0 ? P0[kc*8 + lh*2]     : make_float4(0.f,0.f,0.f,0.f);
            xb[kc][0] = vv0 ? P0[kc*8 + lh*2 + 1] : make_float4(0.f,0.f,0.f,0.f);
            xa[kc][1] = vv1 ? P1[kc*8 + lh*2]     : make_float4(0.f,0.f,0.f,0.f);
            xb[kc][1] = vv1 ? P1[kc*8 + lh*2 + 1] : make_float4(0.f,0.f,0.f,0.f);
        }
        #pragma unroll
        for (int kc = 0; kc < 4; ++kc)
            #pragma unroll
            for (int g = 0; g < 2; ++g) {
                xfr[kc][g][0] = f2bf(xa[kc][g].x);
                xfr[kc][g][1] = f2bf(xa[kc][g].y);
                xfr[kc][g][2] = f2bf(xa[kc][g].z);
                xfr[kc][g][3] = f2bf(xa[kc][g].w);
                xfr[kc][g][4] = f2bf(xb[kc][g].x);
                xfr[kc][g][5] = f2bf(xb[kc][g].y);
                xfr[kc][g][6] = f2bf(xb[kc][g].z);
                xfr[kc][g][7] = f2bf(xb[kc][g].w);
            }
    }

    __syncthreads();   // drains vmcnt (global_load_lds) + barrier

    f32x4 acc[8][2];
    #pragma unroll
    for (int n = 0; n < 8; ++n) { acc[n][0] = (f32x4)0.f; acc[n][1] = (f32x4)0.f; }

    #pragma unroll
    for (int kc = 0; kc < 4; ++kc) {
        short8 wf[8];
        #pragma unroll
        for (int n = 0; n < 8; ++n)
            wf[n] = *(const short8*)&lw[((n*4 + kc)*64 + lane) * 8];
        #pragma unroll
        for (int n = 0; n < 8; ++n) {
            acc[n][0] = __builtin_amdgcn_mfma_f32_16x16x32_bf16(wf[n], xfr[kc][0], acc[n][0], 0, 0, 0);
            acc[n][1] = __builtin_amdgcn_mfma_f32_16x16x32_bf16(wf[n], xfr[kc][1], acc[n][1], 0, 0, 0);
        }
    }

    #pragma unroll
    for (int g = 0; g < 2; ++g) {
        int row = rowbase + g*16 + l15;
        if (row >= nrows) continue;
        #pragma unroll
        for (int n = 0; n < 8; ++n) {
            float4 b4 = *(const float4*)&bias[n*16 + lh*4];
            float y0 = acc[n][g][0] + b4.x;
            float y1 = acc[n][g][1] + b4.y;
            float y2 = acc[n][g][2] + b4.z;
            float y3 = acc[n][g][3] + b4.w;
            if (OUT_BF16) {
                short4v s; s[0]=f2bf(y0); s[1]=f2bf(y1); s[2]=f2bf(y2); s[3]=f2bf(y3);
                *(short4v*)&((short*)Yv)[(size_t)row * 128 + n*16 + lh*4] = s;
            } else {
                *(float4*)&((float*)Yv)[(size_t)row * 128 + n*16 + lh*4] =
                    make_float4(y0, y1, y2, y3);
            }
        }
    }
}

// Output projection: bf16 in, fp32 out.
__global__ __launch_bounds__(256) void gemm_out_kernel(
    const short* __restrict__ Xb, int nrows,
    const short* __restrict__ Wb, const float* __restrict__ bias,
    float* __restrict__ Y)
{
    gemm_body<true, false>(Xb, nrows, Wb, bias, Y, blockIdx.x);
}

// Fused QKV with XCD co-location: slices of X-tile x at b=(x&7)+8*(3*(x>>3)+w)
// share b%8 (same XCD) and are time-aligned -> X fetched once per XCD.
__global__ __launch_bounds__(256) void gemm_qkv_kernel(
    const float* __restrict__ X, int nrows, int nxblk,
    const short* __restrict__ WB,
    const float* __restrict__ bq, const float* __restrict__ bk,
    const float* __restrict__ bv,
    short* __restrict__ Yb, size_t slice)
{
    int b = blockIdx.x;
    int k = b & 7, j = b >> 3;
    int jd = j / 3, w = j - 3 * jd;
    int x = k + 8 * jd;
    if (x >= nxblk) return;
    const float* bias = (w == 0) ? bq : (w == 1) ? bk : bv;
    gemm_body<false, true>(X, nrows, WB + w * 16384, bias,
                           Yb + (size_t)w * slice, x);
}

// ---------------------------------------------------------------------------
// init: zero deg + zero degree bins + detect int64-vs-int32 edge_index.
// ---------------------------------------------------------------------------
__global__ void init_kernel(int* __restrict__ deg, int n,
                            int* __restrict__ dbin,
                            const int* __restrict__ raw, int* __restrict__ flag)
{
    int i = blockIdx.x * TPB + threadIdx.x;
    if (i < n) deg[i] = 0;
    if (blockIdx.x == 0 && threadIdx.x < 64) dbin[threadIdx.x] = 0;
    if (blockIdx.x == 0 && threadIdx.x == 0) {
        int odd_nonzero = 0;
        for (int k = 0; k < 128; ++k)
            if (raw[2 * k + 1] != 0) odd_nonzero = 1;
        *flag = odd_nonzero ? 0 : 1;  // 1 => int64 layout
    }
}

// ---------------------------------------------------------------------------
// conv_hist + wconv fused (r13, validated).
// ---------------------------------------------------------------------------
__global__ void conv_hist_wconv_kernel(
    const void* __restrict__ raw, int E, const int* __restrict__ flag,
    int* __restrict__ out, int* __restrict__ deg, int ebC,
    const float* __restrict__ W0, const float* __restrict__ W1,
    const float* __restrict__ W2, const float* __restrict__ W3,
    short* __restrict__ WB)
{
    int b = blockIdx.x;
    if (b < ebC) {
        int i = b * TPB + threadIdx.x;
        if (i >= 2 * E) return;
        int v;
        if (*flag) v = (int)((const long long*)raw)[i];
        else       v = ((const int*)raw)[i];
        out[i] = v;
        if (i < E) atomicAdd(&deg[v], 1);
    } else {
        int i = (b - ebC) * TPB + threadIdx.x;   // 0..65535
        if (i >= 65536) return;
        const float* W = (i < 16384) ? W0 : (i < 32768) ? W1 : (i < 49152) ? W2 : W3;
        WB[i] = f2bf(W[i & 16383]);
    }
}

// ---------------------------------------------------------------------------
// CSR scan chain; scan1 histograms degrees via per-block LDS bins (64 global
// atomics per block, NOT per node — r17's contention bug fixed).
// ---------------------------------------------------------------------------
__global__ void scan1_kernel(const int* __restrict__ deg, int n,
                             int* __restrict__ rowstart, int* __restrict__ bsum,
                             int* __restrict__ dbin)
{
    __shared__ int sm[TPB];
    __shared__ int lbin[64];
    int t = threadIdx.x;
    if (t < 64) lbin[t] = 0;
    int gid = blockIdx.x * TPB + t;
    int v = (gid < n) ? deg[gid] : 0;
    __syncthreads();
    if (gid < n) atomicAdd(&lbin[v < 63 ? v : 63], 1);   // LDS atomic
    sm[t] = v;
    __syncthreads();
    for (int off = 1; off < TPB; off <<= 1) {
        int x = (t >= off) ? sm[t - off] : 0;
        __syncthreads();
        sm[t] += x;
        __syncthreads();
    }
    if (gid < n) rowstart[gid] = sm[t] - v;
    if (t == TPB - 1) bsum[blockIdx.x] = sm[t];
    if (t < 64 && lbin[t] > 0) atomicAdd(&dbin[t], lbin[t]);  // 64/block, spread
}

__global__ void scan2_kernel(int* __restrict__ bsum, int nb)
{
    __shared__ int sm[512];
    int t = threadIdx.x;
    int v = (t < nb) ? bsum[t] : 0;
    sm[t] = v;
    __syncthreads();
    for (int off = 1; off < 512; off <<= 1) {
        int x = (t >= off) ? sm[t - off] : 0;
        __syncthreads();
        sm[t] += x;
        __syncthreads();
    }
    if (t < nb) bsum[t] = sm[t] - v;
}

__global__ void scan3_kernel(int* __restrict__ rowstart, int* __restrict__ cursor,
                             int n, int E, const int* __restrict__ bsum)
{
    int gid = blockIdx.x * TPB + threadIdx.x;
    if (gid < n) {
        int v = rowstart[gid] + bsum[blockIdx.x];
        rowstart[gid] = v;
        cursor[gid] = v;
    }
    if (gid == 0) rowstart[n] = E;
}

// Exclusive scan of the 64 degree bins -> per-bin global cursors.
__global__ void scan_deg_kernel(const int* __restrict__ dbin, int* __restrict__ dcur)
{
    __shared__ int sm[64];
    int t = threadIdx.x;   // 64 threads
    int v = dbin[t];
    sm[t] = v;
    __syncthreads();
    for (int off = 1; off < 64; off <<= 1) {
        int x = (t >= off) ? sm[t - off] : 0;
        __syncthreads();
        sm[t] += x;
        __syncthreads();
    }
    dcur[t] = sm[t] - v;
}

// Two-level counting-sort scatter: per-block LDS histogram + chunk reservation
// (64 global atomics per block), then conflict-free scatter.
__global__ void fill_perm_kernel(const int* __restrict__ deg, int n,
                                 int* __restrict__ dcur, int* __restrict__ nodeperm)
{
    __shared__ int lbin[64], lbase[64];
    int t = threadIdx.x;
    if (t < 64) lbin[t] = 0;
    __syncthreads();
    int i = blockIdx.x * TPB + t;
    int d = 0, lpos = 0;
    bool valid = i < n;
    if (valid) {
        d = deg[i]; if (d > 63) d = 63;
        lpos = atomicAdd(&lbin[d], 1);            // LDS atomic
    }
    __syncthreads();
    if (t < 64) lbase[t] = lbin[t] ? atomicAdd(&dcur[t], lbin[t]) : 0;
    __syncthreads();
    if (valid) nodeperm[lbase[d] + lpos] = i;
}

// Bin edges by destination: ecol[p] = source col, erow[p] = dest row.
__global__ void fill_kernel(const int* __restrict__ ei, int E,
                            int* __restrict__ cursor,
                            int* __restrict__ ecol, int* __restrict__ erow)
{
    int e = blockIdx.x * TPB + threadIdx.x;
    if (e >= E) return;
    int r = ei[e];
    int pos = atomicAdd(&cursor[r], 1);
    ecol[pos] = ei[E + e];
    erow[pos] = r;
}

// ---------------------------------------------------------------------------
// EDGE-PARALLEL scores + fused online softmax partials (r14, validated).
// ---------------------------------------------------------------------------
__global__ __launch_bounds__(256) void epar_score_stats_kernel(
    const short* __restrict__ Qb, const short* __restrict__ Kb,
    const int* __restrict__ erow, const int* __restrict__ ecol, int EH,
    float* __restrict__ S, float* __restrict__ mpart, float* __restrict__ zpart)
{
    int t = threadIdx.x;
    int stride = gridDim.x * TPB;
    float m = -3.0e38f, z = 0.f;
    for (int idx = blockIdx.x * TPB + t; idx < EH; idx += stride) {
        int p = idx >> 3, h = idx & 7;
        int r = erow[p], c = ecol[p];
        const short8* q8 = (const short8*)(Qb + (size_t)r * 128 + h * 16);
        const short8* k8 = (const short8*)(Kb + (size_t)c * 128 + h * 16);
        short8 q0 = q8[0], q1 = q8[1], k0 = k8[0], k1 = k8[1];
        float dot = 0.f;
        #pragma unroll
        for (int i = 0; i < 8; ++i) {
            dot += bf2f(q0[i]) * bf2f(k0[i]);
            dot += bf2f(q1[i]) * bf2f(k1[i]);
        }
        float s = dot * 0.25f;   // 1/sqrt(16)
        S[idx] = s;
        float M = fmaxf(m, s);
        z = z * __expf(m - M) + __expf(s - M);
        m = M;
    }
    __shared__ float sm[TPB], sz[TPB];
    sm[t] = m; sz[t] = z;
    __syncthreads();
    for (int off = 128; off >= 8; off >>= 1) {
        if (t < off) {
            float m2 = sm[t + off], z2 = sz[t + off];
            float M = fmaxf(sm[t], m2);
            sz[t] = sz[t] * __expf(sm[t] - M) + z2 * __expf(m2 - M);
            sm[t] = M;
        }
        __syncthreads();
    }
    if (t < 8) {
        mpart[blockIdx.x * 8 + t] = sm[t];
        zpart[blockIdx.x * 8 + t] = sz[t];
    }
}

// One block: combine nb per-block partials -> MZ[h] (max), MZ[8+h] (Z).
__global__ void stats_reduce_kernel(const float* __restrict__ mpart,
                                    const float* __restrict__ zpart,
                                    int nb, float* __restrict__ MZ)
{
    int t = threadIdx.x;
    int h = t & 7, chunk = t >> 3;   // 32 chunks
    float m = -3.0e38f, z = 0.f;
    for (int i = chunk; i < nb; i += 32) {
        float m2 = mpart[i * 8 + h], z2 = zpart[i * 8 + h];
        float M = fmaxf(m, m2);
        z = z * __expf(m - M) + z2 * __expf(m2 - M);
        m = M;
    }
    __shared__ float sm[TPB], sz[TPB];
    sm[t] = m; sz[t] = z;
    __syncthreads();
    for (int off = 128; off >= 8; off >>= 1) {
        if (t < off) {
            float m2 = sm[t + off], z2 = sz[t + off];
            float M = fmaxf(sm[t], m2);
            sz[t] = sz[t] * __expf(sm[t] - M) + z2 * __expf(m2 - M);
            sm[t] = M;
        }
        __syncthreads();
    }
    if (t < 8) { MZ[t] = sm[t]; MZ[8 + t] = sz[t]; }
}

// ---------------------------------------------------------------------------
// Gather segment-sum over DEGREE-SORTED nodes (nodeperm), fused exp/normalize,
// depth-2 prefetch. Waves see near-uniform degrees -> no wave-max skew.
// ---------------------------------------------------------------------------
__global__ __launch_bounds__(256) void gather_kernel(
    const float* __restrict__ S, const short* __restrict__ Vb,
    const int* __restrict__ ecol,
    const int* __restrict__ rowstart,
    const int* __restrict__ nodeperm,
    const float* __restrict__ MZ, int N,
    short* __restrict__ outb)
{
    int idx = blockIdx.x * TPB + threadIdx.x;
    if (idx >= N * 8) return;
    int node = nodeperm[idx >> 3];
    int h = idx & 7;
    float M = MZ[h];
    float invZ = 1.0f / MZ[8 + h];
    int p0 = rowstart[node], p1 = rowstart[node + 1];

    float a[16];
    #pragma unroll
    for (int i = 0; i < 16; ++i) a[i] = 0.f;

    if (p0 < p1) {
        short8 va0, va1, vb0, vb1;
        float sa, sb;
        {
            const short8* vp = (const short8*)(Vb + (size_t)ecol[p0] * 128 + h * 16);
            va0 = vp[0]; va1 = vp[1];
            sa = S[(size_t)p0 * 8 + h];
        }
        if (p0 + 1 < p1) {
            const short8* vp = (const short8*)(Vb + (size_t)ecol[p0+1] * 128 + h * 16);
            vb0 = vp[0]; vb1 = vp[1];
            sb = S[(size_t)(p0+1) * 8 + h];
        } else { vb0 = va0; vb1 = va1; sb = sa; }

        for (int p = p0; p < p1; ++p) {
            short8 vc0 = vb0, vc1 = vb1;
            float sc = sb;
            if (p + 2 < p1) {
                const short8* vp = (const short8*)(Vb + (size_t)ecol[p+2] * 128 + h * 16);
                vc0 = vp[0]; vc1 = vp[1];
                sc = S[(size_t)(p+2) * 8 + h];
            }
            float w = __expf(sa - M) * invZ;
            #pragma unroll
            for (int i = 0; i < 8; ++i) {
                a[i]     += w * bf2f(va0[i]);
                a[8 + i] += w * bf2f(va1[i]);
            }
            va0 = vb0; va1 = vb1; vb0 = vc0; vb1 = vc1;
            sa = sb; sb = sc;
        }
    }
    short8 o0, o1;
    #pragma unroll
    for (int i = 0; i < 8; ++i) { o0[i] = f2bf(a[i]); o1[i] = f2bf(a[8 + i]); }
    short8* ob = (short8*)(outb + (size_t)node * 128 + h * 16);
    ob[0] = o0; ob[1] = o1;
}

// ---------------------------------------------------------------------------
extern "C" void kernel_launch(void* const* d_in, const int* in_sizes, int n_in,
                              void* d_out, int out_size, void* d_ws, size_t ws_size,
                              hipStream_t stream)
{
    const float* feat = (const float*)d_in[0];
    const void*  eraw = d_in[1];
    const float* Wq = (const float*)d_in[2];
    const float* bq = (const float*)d_in[3];
    const float* Wk = (const float*)d_in[4];
    const float* bk = (const float*)d_in[5];
    const float* Wv = (const float*)d_in[6];
    const float* bv = (const float*)d_in[7];
    const float* Wo = (const float*)d_in[8];
    const float* bo = (const float*)d_in[9];

    const int N = in_sizes[0] / 128;
    const int E = in_sizes[1] / 2;
    const size_t NC = (size_t)N * 128;
    const int EH = E * 8;
    const int gbN = (N * 8 + TPB - 1) / TPB;   // node-head grid (gather)
    const int EG  = 2500;                      // edge-stats grid (grid-stride)

    // Workspace layout
    short* Qb   = (short*)d_ws;            // [N][128] bf16 (Q,K,V contiguous)
    short* Kb   = Qb + NC;
    short* Vb   = Kb + NC;
    short* ACCb = Vb + NC;                 // [N][128] bf16
    float* S    = (float*)(ACCb + NC);     // [E*8] scores, CSR order
    int*   EI   = (int*)(S + EH);          // int32 indices, 2*E
    short* WB   = (short*)(EI + 2 * E);    // 4 x 16384 bf16 weights
    float* mpart = (float*)(WB + 65536);   // [EG][8]
    float* zpart = mpart + (size_t)EG * 8;
    float* MZ    = zpart + (size_t)EG * 8; // 16: M[8], Z[8]
    int*   flag  = (int*)(MZ + 16);
    int* deg      = flag + 16;             // N
    int* rowstart = deg + N;               // N+1
    int* cursor   = rowstart + N + 1;      // N
    int* bsum     = cursor + N;            // 512
    int* ecol     = bsum + 512;            // E (binned source cols)
    int* erow     = ecol + E;              // E (binned dest rows)
    int* dbin     = erow + E;              // 64 degree bins
    int* dcur     = dbin + 64;             // 64 bin cursors
    int* nodeperm = dcur + 64;             // N (degree-sorted node order)

    const int nbS = (N + TPB - 1) / TPB;
    const int ebE = (E + TPB - 1) / TPB;
    const int ebC = (2 * E + TPB - 1) / TPB;

    // --- CSR build + degree sort (independent of GEMMs) ---
    init_kernel<<<nbS, TPB, 0, stream>>>(deg, N, dbin, (const int*)eraw, flag);
    conv_hist_wconv_kernel<<<ebC + 256, TPB, 0, stream>>>(
        eraw, E, flag, EI, deg, ebC, Wq, Wk, Wv, Wo, WB);
    scan1_kernel<<<nbS, TPB, 0, stream>>>(deg, N, rowstart, bsum, dbin);
    scan2_kernel<<<1, 512, 0, stream>>>(bsum, nbS);
    scan3_kernel<<<nbS, TPB, 0, stream>>>(rowstart, cursor, N, E, bsum);
    scan_deg_kernel<<<1, 64, 0, stream>>>(dbin, dcur);
    fill_kernel<<<ebE, TPB, 0, stream>>>(EI, E, cursor, ecol, erow);
    fill_perm_kernel<<<nbS, TPB, 0, stream>>>(deg, N, dcur, nodeperm);

    // --- Projections (r15 structure) ---
    const int gb = (N + 127) / 128;                 // X tiles
    const int qkvgrid = 8 * 3 * ((gb + 7) / 8);     // XCD-co-located mapping
    gemm_qkv_kernel<<<qkvgrid, TPB, 0, stream>>>(feat, N, gb, WB, bq, bk, bv, Qb, NC);

    // --- Scores + softmax stats (edge-parallel, CSR order) ---
    epar_score_stats_kernel<<<EG, TPB, 0, stream>>>(Qb, Kb, erow, ecol, EH,
                                                    S, mpart, zpart);
    stats_reduce_kernel<<<1, TPB, 0, stream>>>(mpart, zpart, EG, MZ);

    // --- Gather segment-sum (degree-sorted) -> bf16 ACC ---
    gather_kernel<<<gbN, TPB, 0, stream>>>(S, Vb, ecol, rowstart, nodeperm,
                                           MZ, N, ACCb);

    // --- Output projection (bf16 in, fp32 out) ---
    gemm_out_kernel<<<gb, TPB, 0, stream>>>(ACCb, N, WB + 3 * 16384, bo, (float*)d_out);
}

// Round 19
// 246.951 us; speedup vs baseline: 3.9172x; 1.0563x over previous
//
#include <hip/hip_runtime.h>

// HyperbolicAttention: N=100000 nodes, C=128, H=8 heads, D=16, E=640000 edges.
// FINAL (r15 revert — best validated at 248.9us):
//   - GEMMs: one-shot 128-row MFMA blocks, all loads up front, W staged via
//     async global_load_lds (frag-major LDS), swapped-operand MFMA,
//     XCD-co-located time-aligned QKV slices. (Persistent / independent-wave /
//     flash-fused / paired variants all measured slower.)
//   - Edge pipeline: CSR-first; edge-parallel scores with fused online
//     softmax stats; node-parallel gather with depth-2 prefetch.
//     (Head-major layout and degree-sorting both measured slower.)

#define TPB 256

typedef __attribute__((ext_vector_type(8))) short short8;
typedef __attribute__((ext_vector_type(4))) short short4v;
typedef __attribute__((ext_vector_type(4))) float f32x4;

// fp32 -> bf16 round-to-nearest-even
__device__ __forceinline__ short f2bf(float f) {
    unsigned u = __float_as_uint(f);
    u += 0x7fffu + ((u >> 16) & 1u);
    return (short)(u >> 16);
}
// bf16 -> fp32
__device__ __forceinline__ float bf2f(short s) {
    return __uint_as_float(((unsigned)(unsigned short)s) << 16);
}

// ---------------------------------------------------------------------------
// Shared GEMM body: one 128-row tile per block; W staged to LDS via async
// global_load_lds (frag-major); all X loads issued before any wait;
// swapped-operand MFMA; vectorized stores.
// ---------------------------------------------------------------------------
template<bool IN_BF16, bool OUT_BF16>
__device__ __forceinline__ void gemm_body(
    const void* __restrict__ Xv, int nrows,
    const short* __restrict__ Wb, const float* __restrict__ bias,
    void* __restrict__ Yv, int xblk)
{
    __shared__ short lw[16384];   // 32 KiB W, frag-major
    const int tid = threadIdx.x;

    // --- stage W: async global->LDS, 8 x 16B per thread, no reg round-trip ---
    #pragma unroll
    for (int r = 0; r < 8; ++r) {
        int c = r * 256 + tid;              // chunk id 0..2047
        int fragid = c >> 6, ln = c & 63;
        int n = fragid >> 2, kc = fragid & 3;
        const short* gsrc = &Wb[(n*16 + (ln & 15))*128 + kc*32 + (ln >> 4)*8];
        __builtin_amdgcn_global_load_lds(
            (const __attribute__((address_space(1))) void*)gsrc,
            (__attribute__((address_space(3))) void*)&lw[c * 8],
            16, 0, 0);
    }

    const int wid = tid >> 6;
    const int lane = tid & 63;
    const int l15 = lane & 15;
    const int lh  = lane >> 4;
    const int rowbase = xblk * 128 + wid * 32;
    const int r0 = rowbase + l15, r1 = r0 + 16;
    const bool vv0 = r0 < nrows, vv1 = r1 < nrows;

    // --- issue ALL X loads, then convert ---
    short8 xfr[4][2];   // [kc][row-group]
    if (IN_BF16) {
        const short* Xb = (const short*)Xv;
        #pragma unroll
        for (int kc = 0; kc < 4; ++kc) {
            xfr[kc][0] = vv0 ? *(const short8*)&Xb[(size_t)r0*128 + kc*32 + lh*8]
                             : (short8)(short)0;
            xfr[kc][1] = vv1 ? *(const short8*)&Xb[(size_t)r1*128 + kc*32 + lh*8]
                             : (short8)(short)0;
        }
    } else {
        const float* Xf = (const float*)Xv;
        const float4* P0 = (const float4*)(Xf + (size_t)r0 * 128);
        const float4* P1 = (const float4*)(Xf + (size_t)r1 * 128);
        float4 xa[4][2], xb[4][2];
        #pragma unroll
        for (int kc = 0; kc < 4; ++kc) {
            xa[kc][0] = vv0 ? P0[kc*8 + lh*2]     : make_float4(0.f,0.f,0.f,0.f);
            xb[kc][0] = vv0 ? P0[kc*8 + lh*2 + 1] : make_float4(0.f,0.f,0.f,0.f);
            xa[kc][1] = vv1 ? P1[kc*8 + lh*2]     : make_float4(0.f,0.f,0.f,0.f);
            xb[kc][1] = vv1 ? P1[kc*8 + lh*2 + 1] : make_float4(0.f,0.f,0.f,0.f);
        }
        #pragma unroll
        for (int kc = 0; kc < 4; ++kc)
            #pragma unroll
            for (int g = 0; g < 2; ++g) {
                xfr[kc][g][0] = f2bf(xa[kc][g].x);
                xfr[kc][g][1] = f2bf(xa[kc][g].y);
                xfr[kc][g][2] = f2bf(xa[kc][g].z);
                xfr[kc][g][3] = f2bf(xa[kc][g].w);
                xfr[kc][g][4] = f2bf(xb[kc][g].x);
                xfr[kc][g][5] = f2bf(xb[kc][g].y);
                xfr[kc][g][6] = f2bf(xb[kc][g].z);
                xfr[kc][g][7] = f2bf(xb[kc][g].w);
            }
    }

    __syncthreads();   // drains vmcnt (global_load_lds) + barrier

    f32x4 acc[8][2];
    #pragma unroll
    for (int n = 0; n < 8; ++n) { acc[n][0] = (f32x4)0.f; acc[n][1] = (f32x4)0.f; }

    #pragma unroll
    for (int kc = 0; kc < 4; ++kc) {
        short8 wf[8];
        #pragma unroll
        for (int n = 0; n < 8; ++n)
            wf[n] = *(const short8*)&lw[((n*4 + kc)*64 + lane) * 8];
        #pragma unroll
        for (int n = 0; n < 8; ++n) {
            acc[n][0] = __builtin_amdgcn_mfma_f32_16x16x32_bf16(wf[n], xfr[kc][0], acc[n][0], 0, 0, 0);
            acc[n][1] = __builtin_amdgcn_mfma_f32_16x16x32_bf16(wf[n], xfr[kc][1], acc[n][1], 0, 0, 0);
        }
    }

    #pragma unroll
    for (int g = 0; g < 2; ++g) {
        int row = rowbase + g*16 + l15;
        if (row >= nrows) continue;
        #pragma unroll
        for (int n = 0; n < 8; ++n) {
            float4 b4 = *(const float4*)&bias[n*16 + lh*4];
            float y0 = acc[n][g][0] + b4.x;
            float y1 = acc[n][g][1] + b4.y;
            float y2 = acc[n][g][2] + b4.z;
            float y3 = acc[n][g][3] + b4.w;
            if (OUT_BF16) {
                short4v s; s[0]=f2bf(y0); s[1]=f2bf(y1); s[2]=f2bf(y2); s[3]=f2bf(y3);
                *(short4v*)&((short*)Yv)[(size_t)row * 128 + n*16 + lh*4] = s;
            } else {
                *(float4*)&((float*)Yv)[(size_t)row * 128 + n*16 + lh*4] =
                    make_float4(y0, y1, y2, y3);
            }
        }
    }
}

// Output projection: bf16 in, fp32 out.
__global__ __launch_bounds__(256) void gemm_out_kernel(
    const short* __restrict__ Xb, int nrows,
    const short* __restrict__ Wb, const float* __restrict__ bias,
    float* __restrict__ Y)
{
    gemm_body<true, false>(Xb, nrows, Wb, bias, Y, blockIdx.x);
}

// Fused QKV with XCD co-location: slices of X-tile x at b=(x&7)+8*(3*(x>>3)+w)
// share b%8 (same XCD) and are time-aligned -> X fetched once per XCD.
__global__ __launch_bounds__(256) void gemm_qkv_kernel(
    const float* __restrict__ X, int nrows, int nxblk,
    const short* __restrict__ WB,
    const float* __restrict__ bq, const float* __restrict__ bk,
    const float* __restrict__ bv,
    short* __restrict__ Yb, size_t slice)
{
    int b = blockIdx.x;
    int k = b & 7, j = b >> 3;
    int jd = j / 3, w = j - 3 * jd;
    int x = k + 8 * jd;
    if (x >= nxblk) return;
    const float* bias = (w == 0) ? bq : (w == 1) ? bk : bv;
    gemm_body<false, true>(X, nrows, WB + w * 16384, bias,
                           Yb + (size_t)w * slice, x);
}

// ---------------------------------------------------------------------------
// init: zero deg (grid-stride) + detect int64-vs-int32 edge_index (block 0).
// ---------------------------------------------------------------------------
__global__ void init_kernel(int* __restrict__ deg, int n,
                            const int* __restrict__ raw, int* __restrict__ flag)
{
    int i = blockIdx.x * TPB + threadIdx.x;
    if (i < n) deg[i] = 0;
    if (blockIdx.x == 0 && threadIdx.x == 0) {
        int odd_nonzero = 0;
        for (int k = 0; k < 128; ++k)
            if (raw[2 * k + 1] != 0) odd_nonzero = 1;
        *flag = odd_nonzero ? 0 : 1;  // 1 => int64 layout
    }
}

// ---------------------------------------------------------------------------
// conv_hist + wconv fused: blocks [0, ebC) convert edge_index + histogram;
// blocks [ebC, ebC+256) convert the 4 weight matrices to bf16.
// ---------------------------------------------------------------------------
__global__ void conv_hist_wconv_kernel(
    const void* __restrict__ raw, int E, const int* __restrict__ flag,
    int* __restrict__ out, int* __restrict__ deg, int ebC,
    const float* __restrict__ W0, const float* __restrict__ W1,
    const float* __restrict__ W2, const float* __restrict__ W3,
    short* __restrict__ WB)
{
    int b = blockIdx.x;
    if (b < ebC) {
        int i = b * TPB + threadIdx.x;
        if (i >= 2 * E) return;
        int v;
        if (*flag) v = (int)((const long long*)raw)[i];
        else       v = ((const int*)raw)[i];
        out[i] = v;
        if (i < E) atomicAdd(&deg[v], 1);
    } else {
        int i = (b - ebC) * TPB + threadIdx.x;   // 0..65535
        if (i >= 65536) return;
        const float* W = (i < 16384) ? W0 : (i < 32768) ? W1 : (i < 49152) ? W2 : W3;
        WB[i] = f2bf(W[i & 16383]);
    }
}

// ---------------------------------------------------------------------------
// CSR scan chain.
// ---------------------------------------------------------------------------
__global__ void scan1_kernel(const int* __restrict__ deg, int n,
                             int* __restrict__ rowstart, int* __restrict__ bsum)
{
    __shared__ int sm[TPB];
    int t = threadIdx.x;
    int gid = blockIdx.x * TPB + t;
    int v = (gid < n) ? deg[gid] : 0;
    sm[t] = v;
    __syncthreads();
    for (int off = 1; off < TPB; off <<= 1) {
        int x = (t >= off) ? sm[t - off] : 0;
        __syncthreads();
        sm[t] += x;
        __syncthreads();
    }
    if (gid < n) rowstart[gid] = sm[t] - v;
    if (t == TPB - 1) bsum[blockIdx.x] = sm[t];
}

__global__ void scan2_kernel(int* __restrict__ bsum, int nb)
{
    __shared__ int sm[512];
    int t = threadIdx.x;
    int v = (t < nb) ? bsum[t] : 0;
    sm[t] = v;
    __syncthreads();
    for (int off = 1; off < 512; off <<= 1) {
        int x = (t >= off) ? sm[t - off] : 0;
        __syncthreads();
        sm[t] += x;
        __syncthreads();
    }
    if (t < nb) bsum[t] = sm[t] - v;
}

__global__ void scan3_kernel(int* __restrict__ rowstart, int* __restrict__ cursor,
                             int n, int E, const int* __restrict__ bsum)
{
    int gid = blockIdx.x * TPB + threadIdx.x;
    if (gid < n) {
        int v = rowstart[gid] + bsum[blockIdx.x];
        rowstart[gid] = v;
        cursor[gid] = v;
    }
    if (gid == 0) rowstart[n] = E;
}

// Bin edges by destination: ecol[p] = source col, erow[p] = dest row.
__global__ void fill_kernel(const int* __restrict__ ei, int E,
                            int* __restrict__ cursor,
                            int* __restrict__ ecol, int* __restrict__ erow)
{
    int e = blockIdx.x * TPB + threadIdx.x;
    if (e >= E) return;
    int r = ei[e];
    int pos = atomicAdd(&cursor[r], 1);
    ecol[pos] = ei[E + e];
    erow[pos] = r;
}

// ---------------------------------------------------------------------------
// EDGE-PARALLEL scores + fused online softmax partials.
// thread = (CSR position p, head h=idx&7), grid-stride (stride multiple of 8
// keeps the head class fixed per thread). Perfect load balance; S sequential;
// consecutive p share Q rows (CSR-sorted) -> L1 hits.
// ---------------------------------------------------------------------------
__global__ __launch_bounds__(256) void epar_score_stats_kernel(
    const short* __restrict__ Qb, const short* __restrict__ Kb,
    const int* __restrict__ erow, const int* __restrict__ ecol, int EH,
    float* __restrict__ S, float* __restrict__ mpart, float* __restrict__ zpart)
{
    int t = threadIdx.x;
    int stride = gridDim.x * TPB;
    float m = -3.0e38f, z = 0.f;
    for (int idx = blockIdx.x * TPB + t; idx < EH; idx += stride) {
        int p = idx >> 3, h = idx & 7;
        int r = erow[p], c = ecol[p];
        const short8* q8 = (const short8*)(Qb + (size_t)r * 128 + h * 16);
        const short8* k8 = (const short8*)(Kb + (size_t)c * 128 + h * 16);
        short8 q0 = q8[0], q1 = q8[1], k0 = k8[0], k1 = k8[1];
        float dot = 0.f;
        #pragma unroll
        for (int i = 0; i < 8; ++i) {
            dot += bf2f(q0[i]) * bf2f(k0[i]);
            dot += bf2f(q1[i]) * bf2f(k1[i]);
        }
        float s = dot * 0.25f;   // 1/sqrt(16)
        S[idx] = s;
        float M = fmaxf(m, s);
        z = z * __expf(m - M) + __expf(s - M);
        m = M;
    }
    __shared__ float sm[TPB], sz[TPB];
    sm[t] = m; sz[t] = z;
    __syncthreads();
    for (int off = 128; off >= 8; off >>= 1) {
        if (t < off) {
            float m2 = sm[t + off], z2 = sz[t + off];
            float M = fmaxf(sm[t], m2);
            sz[t] = sz[t] * __expf(sm[t] - M) + z2 * __expf(m2 - M);
            sm[t] = M;
        }
        __syncthreads();
    }
    if (t < 8) {
        mpart[blockIdx.x * 8 + t] = sm[t];
        zpart[blockIdx.x * 8 + t] = sz[t];
    }
}

// One block: combine nb per-block partials -> MZ[h] (max), MZ[8+h] (Z).
__global__ void stats_reduce_kernel(const float* __restrict__ mpart,
                                    const float* __restrict__ zpart,
                                    int nb, float* __restrict__ MZ)
{
    int t = threadIdx.x;
    int h = t & 7, chunk = t >> 3;   // 32 chunks
    float m = -3.0e38f, z = 0.f;
    for (int i = chunk; i < nb; i += 32) {
        float m2 = mpart[i * 8 + h], z2 = zpart[i * 8 + h];
        float M = fmaxf(m, m2);
        z = z * __expf(m - M) + z2 * __expf(m2 - M);
        m = M;
    }
    __shared__ float sm[TPB], sz[TPB];
    sm[t] = m; sz[t] = z;
    __syncthreads();
    for (int off = 128; off >= 8; off >>= 1) {
        if (t < off) {
            float m2 = sm[t + off], z2 = sz[t + off];
            float M = fmaxf(sm[t], m2);
            sz[t] = sz[t] * __expf(sm[t] - M) + z2 * __expf(m2 - M);
            sm[t] = M;
        }
        __syncthreads();
    }
    if (t < 8) { MZ[t] = sm[t]; MZ[8 + t] = sz[t]; }
}

// ---------------------------------------------------------------------------
// Gather segment-sum, fused exp/normalize, depth-2 prefetch.
// thread = (node, head); S sequential; V rows shared by the node's 8 lanes.
// ---------------------------------------------------------------------------
__global__ __launch_bounds__(256) void gather_kernel(
    const float* __restrict__ S, const short* __restrict__ Vb,
    const int* __restrict__ ecol,
    const int* __restrict__ rowstart,
    const float* __restrict__ MZ, int N,
    short* __restrict__ outb)
{
    int idx = blockIdx.x * TPB + threadIdx.x;
    if (idx >= N * 8) return;
    int node = idx >> 3, h = idx & 7;
    float M = MZ[h];
    float invZ = 1.0f / MZ[8 + h];
    int p0 = rowstart[node], p1 = rowstart[node + 1];

    float a[16];
    #pragma unroll
    for (int i = 0; i < 16; ++i) a[i] = 0.f;

    if (p0 < p1) {
        short8 va0, va1, vb0, vb1;
        float sa, sb;
        {
            const short8* vp = (const short8*)(Vb + (size_t)ecol[p0] * 128 + h * 16);
            va0 = vp[0]; va1 = vp[1];
            sa = S[(size_t)p0 * 8 + h];
        }
        if (p0 + 1 < p1) {
            const short8* vp = (const short8*)(Vb + (size_t)ecol[p0+1] * 128 + h * 16);
            vb0 = vp[0]; vb1 = vp[1];
            sb = S[(size_t)(p0+1) * 8 + h];
        } else { vb0 = va0; vb1 = va1; sb = sa; }

        for (int p = p0; p < p1; ++p) {
            short8 vc0 = vb0, vc1 = vb1;
            float sc = sb;
            if (p + 2 < p1) {
                const short8* vp = (const short8*)(Vb + (size_t)ecol[p+2] * 128 + h * 16);
                vc0 = vp[0]; vc1 = vp[1];
                sc = S[(size_t)(p+2) * 8 + h];
            }
            float w = __expf(sa - M) * invZ;
            #pragma unroll
            for (int i = 0; i < 8; ++i) {
                a[i]     += w * bf2f(va0[i]);
                a[8 + i] += w * bf2f(va1[i]);
            }
            va0 = vb0; va1 = vb1; vb0 = vc0; vb1 = vc1;
            sa = sb; sb = sc;
        }
    }
    short8 o0, o1;
    #pragma unroll
    for (int i = 0; i < 8; ++i) { o0[i] = f2bf(a[i]); o1[i] = f2bf(a[8 + i]); }
    short8* ob = (short8*)(outb + (size_t)node * 128 + h * 16);
    ob[0] = o0; ob[1] = o1;
}

// ---------------------------------------------------------------------------
extern "C" void kernel_launch(void* const* d_in, const int* in_sizes, int n_in,
                              void* d_out, int out_size, void* d_ws, size_t ws_size,
                              hipStream_t stream)
{
    const float* feat = (const float*)d_in[0];
    const void*  eraw = d_in[1];
    const float* Wq = (const float*)d_in[2];
    const float* bq = (const float*)d_in[3];
    const float* Wk = (const float*)d_in[4];
    const float* bk = (const float*)d_in[5];
    const float* Wv = (const float*)d_in[6];
    const float* bv = (const float*)d_in[7];
    const float* Wo = (const float*)d_in[8];
    const float* bo = (const float*)d_in[9];

    const int N = in_sizes[0] / 128;
    const int E = in_sizes[1] / 2;
    const size_t NC = (size_t)N * 128;
    const int EH = E * 8;
    const int gbN = (N * 8 + TPB - 1) / TPB;   // node-head grid (gather)
    const int EG  = 2500;                      // edge-stats grid (grid-stride)

    // Workspace layout
    short* Qb   = (short*)d_ws;            // [N][128] bf16 (Q,K,V contiguous)
    short* Kb   = Qb + NC;
    short* Vb   = Kb + NC;
    short* ACCb = Vb + NC;                 // [N][128] bf16
    float* S    = (float*)(ACCb + NC);     // [E*8] scores, CSR order
    int*   EI   = (int*)(S + EH);          // int32 indices, 2*E
    short* WB   = (short*)(EI + 2 * E);    // 4 x 16384 bf16 weights
    float* mpart = (float*)(WB + 65536);   // [EG][8]
    float* zpart = mpart + (size_t)EG * 8;
    float* MZ    = zpart + (size_t)EG * 8; // 16: M[8], Z[8]
    int*   flag  = (int*)(MZ + 16);
    int* deg      = flag + 16;             // N
    int* rowstart = deg + N;               // N+1
    int* cursor   = rowstart + N + 1;      // N
    int* bsum     = cursor + N;            // 512
    int* ecol     = bsum + 512;            // E (binned source cols)
    int* erow     = ecol + E;              // E (binned dest rows)

    const int nbS = (N + TPB - 1) / TPB;
    const int ebE = (E + TPB - 1) / TPB;
    const int ebC = (2 * E + TPB - 1) / TPB;

    // --- CSR build (independent of GEMMs) ---
    init_kernel<<<nbS, TPB, 0, stream>>>(deg, N, (const int*)eraw, flag);
    conv_hist_wconv_kernel<<<ebC + 256, TPB, 0, stream>>>(
        eraw, E, flag, EI, deg, ebC, Wq, Wk, Wv, Wo, WB);
    scan1_kernel<<<nbS, TPB, 0, stream>>>(deg, N, rowstart, bsum);
    scan2_kernel<<<1, 512, 0, stream>>>(bsum, nbS);
    scan3_kernel<<<nbS, TPB, 0, stream>>>(rowstart, cursor, N, E, bsum);
    fill_kernel<<<ebE, TPB, 0, stream>>>(EI, E, cursor, ecol, erow);

    // --- Projections ---
    const int gb = (N + 127) / 128;                 // X tiles
    const int qkvgrid = 8 * 3 * ((gb + 7) / 8);     // XCD-co-located mapping
    gemm_qkv_kernel<<<qkvgrid, TPB, 0, stream>>>(feat, N, gb, WB, bq, bk, bv, Qb, NC);

    // --- Scores + softmax stats (edge-parallel, CSR order) ---
    epar_score_stats_kernel<<<EG, TPB, 0, stream>>>(Qb, Kb, erow, ecol, EH,
                                                    S, mpart, zpart);
    stats_reduce_kernel<<<1, TPB, 0, stream>>>(mpart, zpart, EG, MZ);

    // --- Gather segment-sum with fused exp/normalize -> bf16 ACC ---
    gather_kernel<<<gbN, TPB, 0, stream>>>(S, Vb, ecol, rowstart, MZ, N, ACCb);

    // --- Output projection (bf16 in, fp32 out) ---
    gemm_out_kernel<<<gb, TPB, 0, stream>>>(ACCb, N, WB + 3 * 16384, bo, (float*)d_out);
}